// Round 10
// baseline (4102.522 us; speedup 1.0000x reference)
//
#include <hip/hip_runtime.h>
#include <stdint.h>
#include <stddef.h>

#define NB 1024
#define TB 1024
#define D_IN 6
#define UNITS 64
#define WIDTH 128
#define DOUT 6
#define EPSF 1e-8f
#define SPB 32          // samples per block: tiles E (0-15) and O (16-31), phase-shifted
#define SPT 16          // samples per tile
#define LDK0 108        // c0 row stride (halfs): conflict-free (54 dw == 22 mod 32)
#define LDK 140         // cP/cQ/cG row stride (halfs): conflict-free (70 dw == 6 mod 32)

typedef _Float16 v8h __attribute__((ext_vector_type(8)));
typedef float v4f __attribute__((ext_vector_type(4)));
typedef float v2f __attribute__((ext_vector_type(2)));

#define MFMAH(A,Bf,C) __builtin_amdgcn_mfma_f32_16x16x32_f16((A),(Bf),(C),0,0,0)

// LDS-only barrier: orders LDS across the block, does NOT drain vmcnt.
#define BARRIER_LDS() asm volatile("s_waitcnt lgkmcnt(0)\n\ts_barrier" ::: "memory")

#define C2L2E  2.8853900817779268f    // 2*log2(e)
#define L2E    1.4426950408889634f    // log2(e)
#define NEGL2E (-1.4426950408889634f)

__device__ __forceinline__ float rcp_fast(float x){ return __builtin_amdgcn_rcpf(x); }

// tanh with the 2log2e factor PRE-FOLDED into weights+bias:
// tanh(y) = 1 - 2/(1 + 2^(y*2log2e)); caller passes a2 = y*2log2e (from MFMA).
__device__ __forceinline__ float tanh_from_arg(float a2){
  float u = __builtin_amdgcn_exp2f(a2);
  return fmaf(-2.0f, rcp_fast(u + 1.0f), 1.0f);
}

__device__ __forceinline__ void make_frag1(const float* vals, v8h& hv){
  #pragma unroll
  for (int j = 0; j < 8; j++) hv[j] = (_Float16)vals[j];
}
__device__ __forceinline__ void make_frag2(const float* vals, v8h& hv, v8h& lv){
  #pragma unroll
  for (int j = 0; j < 8; j++){
    _Float16 h = (_Float16)vals[j];
    hv[j] = h;
    lv[j] = (_Float16)(vals[j] - (float)h);
  }
}

// ---- phase bodies as macros (reference enclosing-scope frags; own brace scope) ----
#define PH_A(c0r, cPw) { \
  v8h ah0 = *(const v8h*)((c0r) + mn*LDK0 + 0*32 + q8); \
  v8h ah1 = *(const v8h*)((c0r) + mn*LDK0 + 1*32 + q8); \
  v8h ah2 = *(const v8h*)((c0r) + mn*LDK0 + 2*32 + q8); \
  v4f acc0 = MFMAH(ah0, B0[0][0], E0A); \
  v4f acc1 = MFMAH(ah0, B0[0][1], E0B); \
  acc0 = MFMAH(ah1, B0[1][0], acc0); \
  acc1 = MFMAH(ah1, B0[1][1], acc1); \
  acc0 = MFMAH(ah2, B0[2][0], acc0); \
  acc1 = MFMAH(ah2, B0[2][1], acc1); \
  _Pragma("unroll") \
  for (int r = 0; r < 4; r++){ \
    float u0 = __builtin_amdgcn_exp2f(acc0[r]); \
    float u1 = __builtin_amdgcn_exp2f(acc1[r]); \
    float pp = fmaf(u0, u1, 1.0f); \
    float sm = u0 + u1; \
    (cPw)[(qd*4 + r)*LDK + n] = (_Float16)((pp - sm) * rcp_fast(pp + sm)); \
  } \
}

#define PH_B(cPr, cQw) { \
  v8h bh0 = *(const v8h*)((cPr) + mn*LDK + 0*32 + q8); \
  v8h bh1 = *(const v8h*)((cPr) + mn*LDK + 1*32 + q8); \
  v8h bh2 = *(const v8h*)((cPr) + mn*LDK + 2*32 + q8); \
  v8h bh3 = *(const v8h*)((cPr) + mn*LDK + 3*32 + q8); \
  v4f acc0 = MFMAH(bh0, B1[0][0], E1A); \
  v4f acc1 = MFMAH(bh0, B1[0][1], E1B); \
  acc0 = MFMAH(bh1, B1[1][0], acc0); \
  acc1 = MFMAH(bh1, B1[1][1], acc1); \
  acc0 = MFMAH(bh2, B1[2][0], acc0); \
  acc1 = MFMAH(bh2, B1[2][1], acc1); \
  acc0 = MFMAH(bh3, B1[3][0], acc0); \
  acc1 = MFMAH(bh3, B1[3][1], acc1); \
  _Pragma("unroll") \
  for (int r = 0; r < 4; r++){ \
    float u0 = __builtin_amdgcn_exp2f(acc0[r]); \
    float u1 = __builtin_amdgcn_exp2f(acc1[r]); \
    float pp = fmaf(u0, u1, 1.0f); \
    float sm = u0 + u1; \
    (cQw)[(qd*4 + r)*LDK + n] = (_Float16)((pp - sm) * rcp_fast(pp + sm)); \
  } \
}

#define PH_C(cQr, cGw) { \
  v8h ch0 = *(const v8h*)((cQr) + mn*LDK + 0*32 + q8); \
  v8h ch1 = *(const v8h*)((cQr) + mn*LDK + 1*32 + q8); \
  v8h ch2 = *(const v8h*)((cQr) + mn*LDK + 2*32 + q8); \
  v8h ch3 = *(const v8h*)((cQr) + mn*LDK + 3*32 + q8); \
  v4f acc0 = MFMAH(ch0, B2[0][0], E2A); \
  v4f acc1 = MFMAH(ch0, B2[0][1], E2B); \
  acc0 = MFMAH(ch1, B2[1][0], acc0); \
  acc1 = MFMAH(ch1, B2[1][1], acc1); \
  acc0 = MFMAH(ch2, B2[2][0], acc0); \
  acc1 = MFMAH(ch2, B2[2][1], acc1); \
  acc0 = MFMAH(ch3, B2[3][0], acc0); \
  acc1 = MFMAH(ch3, B2[3][1], acc1); \
  _Pragma("unroll") \
  for (int r = 0; r < 4; r++) \
    (cGw)[(qd*4 + r)*LDK + n] = (_Float16)tanh_from_arg(acc0[r] * acc1[r]); \
}

#define PH_D(cGr, c0w, nrp, hrg, alp_) { \
  v8h gh0 = *(const v8h*)((cGr) + mn*LDK + 0*32 + q8); \
  v8h gh1 = *(const v8h*)((cGr) + mn*LDK + 1*32 + q8); \
  v8h gh2 = *(const v8h*)((cGr) + mn*LDK + 2*32 + q8); \
  v8h gh3 = *(const v8h*)((cGr) + mn*LDK + 3*32 + q8); \
  v4f pA0 = MFMAH(gh0, Bah[0], BSA4); \
  v4f pA1 = MFMAH(gh2, Bah[2], Z4); \
  v4f pB  = MFMAH(gh0, Bbh[0], BSB4); \
  pA0 = MFMAH(gh0, Bal[0], pA0); \
  pA1 = MFMAH(gh2, Bal[2], pA1); \
  pB  = MFMAH(gh1, Bbh[1], pB); \
  pA0 = MFMAH(gh1, Bah[1], pA0); \
  pA1 = MFMAH(gh3, Bah[3], pA1); \
  pB  = MFMAH(gh2, Bbh[2], pB); \
  pA0 = MFMAH(gh1, Bal[1], pA0); \
  pA1 = MFMAH(gh3, Bal[3], pA1); \
  pB  = MFMAH(gh3, Bbh[3], pB); \
  _Pragma("unroll") \
  for (int r = 0; r < 4; r++){ \
    int s = qd*4 + r; \
    float m = (nrp)[s]; \
    float alpha = __builtin_amdgcn_exp2f(pA0[r] + pA1[r]); \
    float beta  = tanh_from_arg(pB[r]); \
    float dec   = __builtin_amdgcn_exp2f(alpha * m); \
    float h = fmaf(dec, (hrg)[r] - beta, beta); \
    (hrg)[r] = h; \
    (c0w)[s*LDK0 + 8 + u] = (_Float16)h; \
    (alp_)[(size_t)r*TB*UNITS] = alpha; \
  } \
  (alp_) += UNITS; \
}

#define WOUT(cb, tt, outp_) { \
  v8h wh0 = *(const v8h*)((cb) + mn*LDK0 + 8 + q8); \
  v8h wh1 = *(const v8h*)((cb) + mn*LDK0 + 40 + q8); \
  v4f acc = MFMAH(wh0, Woh0, Z4); \
  acc = MFMAH(wh1, Woh1, acc); \
  if (mn < DOUT){ \
    _Pragma("unroll") \
    for (int r = 0; r < 4; r++) \
      (outp_)[(size_t)r*TB*DOUT + (size_t)(tt)*DOUT] = acc[r]; \
  } \
}

// wave-4 x-norm for tile with row offset HI (0 or 16); consumes xv (x(t+1)),
// writes xn(t+1)+nrm(t+1), prefetches x(t+2)
#define XNORM(c0w, nrw, HI) { \
  int s = ln & 15; \
  float nv2 = sqrtf(xv0*xv0 + xv1*xv1 + xv2*xv2 + xv3*xv3 + xv4*xv4 + xv5*xv5); \
  (nrw)[s] = nv2 * NEGL2E; \
  float inv = 1.0f / (nv2 + EPSF); \
  (c0w)[s*LDK0 + 0] = (_Float16)(xv0*inv); \
  (c0w)[s*LDK0 + 1] = (_Float16)(xv1*inv); \
  (c0w)[s*LDK0 + 2] = (_Float16)(xv2*inv); \
  (c0w)[s*LDK0 + 3] = (_Float16)(xv3*inv); \
  (c0w)[s*LDK0 + 4] = (_Float16)(xv4*inv); \
  (c0w)[s*LDK0 + 5] = (_Float16)(xv5*inv); \
  int tn = t + 2; if (tn > TB - 1) tn = TB - 1; \
  const v2f* xp2 = (const v2f*)(x + ((size_t)(sgbase + (HI) + s)*TB + (size_t)tn)*D_IN); \
  v2f Dv = xp2[0], Ev = xp2[1], Fv = xp2[2]; \
  xv0 = Dv[0]; xv1 = Dv[1]; xv2 = Ev[0]; xv3 = Ev[1]; xv4 = Fv[0]; xv5 = Fv[1]; \
}

__global__ __launch_bounds__(512, 2) void lmsc_kernel(
    const float* __restrict__ x, const float* __restrict__ initF,
    const float* __restrict__ w10, const float* __restrict__ b10,
    const float* __restrict__ w20, const float* __restrict__ b20,
    const float* __restrict__ w11, const float* __restrict__ b11,
    const float* __restrict__ w21, const float* __restrict__ b21,
    const float* __restrict__ w12, const float* __restrict__ b12,
    const float* __restrict__ w22, const float* __restrict__ b22,
    const float* __restrict__ wa, const float* __restrict__ ba,
    const float* __restrict__ wb, const float* __restrict__ bb,
    const float* __restrict__ wo,
    float* __restrict__ outs, float* __restrict__ alph)
{
  // ---- LDS: ~41 KB (two tiles) ----
  __shared__ __attribute__((aligned(16))) _Float16 c0s[2][2][SPT*LDK0]; // [tile][parity]
  __shared__ __attribute__((aligned(16))) _Float16 cPs[2][SPT*LDK];
  __shared__ __attribute__((aligned(16))) _Float16 cQs[2][SPT*LDK];
  __shared__ __attribute__((aligned(16))) _Float16 cGs[2][SPT*LDK];
  __shared__ __attribute__((aligned(16))) float nrms[2][2][SPT];       // -log2e * ||x||

  const int tid = threadIdx.x;
  const int wv = tid >> 6;       // wave 0..7
  const int ln = tid & 63;
  const int mn = ln & 15;
  const int qd = ln >> 4;
  const int q8 = qd * 8;
  const int n  = wv * 16 + mn;   // col for WIDTH=128 layers (wave owns 16 cols)
  const int sgbase = (int)blockIdx.x * SPB;

  float tmp[8];

  // ---------------- one-time weight fragments (shared by both tiles) ----------
  v8h B0[3][2];
  #pragma unroll
  for (int kf = 0; kf < 3; kf++)
    #pragma unroll
    for (int br = 0; br < 2; br++){
      const float* W = br ? w20 : w10;
      #pragma unroll
      for (int j = 0; j < 8; j++){
        int k = kf*32 + q8 + j;
        int r = (k < 6) ? k : ((k >= 8 && k < 72) ? (k - 2) : -1);
        tmp[j] = (r >= 0) ? W[r*WIDTH + n] * C2L2E : 0.0f;
      }
      make_frag1(tmp, B0[kf][br]);
    }

  v8h B1[4][2], B2[4][2];
  #pragma unroll
  for (int kf = 0; kf < 4; kf++)
    #pragma unroll
    for (int br = 0; br < 2; br++){
      const float* W = br ? w21 : w11;
      #pragma unroll
      for (int j = 0; j < 8; j++)
        tmp[j] = W[(kf*32 + q8 + j)*WIDTH + n] * C2L2E;
      make_frag1(tmp, B1[kf][br]);
      const float* V = br ? w22 : w12;
      const float sc = br ? 1.0f : C2L2E;
      #pragma unroll
      for (int j = 0; j < 8; j++)
        tmp[j] = V[(kf*32 + q8 + j)*WIDTH + n] * sc;
      make_frag1(tmp, B2[kf][br]);
    }

  const int u = (wv & 3) * 16 + mn;
  v8h Bah[4], Bal[4], Bbh[4];
  #pragma unroll
  for (int kf = 0; kf < 4; kf++){
    #pragma unroll
    for (int j = 0; j < 8; j++)
      tmp[j] = wa[(kf*32 + q8 + j)*UNITS + u] * L2E;
    make_frag2(tmp, Bah[kf], Bal[kf]);
    #pragma unroll
    for (int j = 0; j < 8; j++)
      tmp[j] = wb[(kf*32 + q8 + j)*UNITS + u] * C2L2E;
    make_frag1(tmp, Bbh[kf]);
  }

  v8h Woh0, Woh1;
  #pragma unroll
  for (int j = 0; j < 8; j++)
    tmp[j] = (mn < DOUT) ? wo[(q8 + j)*DOUT + mn] : 0.0f;
  make_frag1(tmp, Woh0);
  #pragma unroll
  for (int j = 0; j < 8; j++)
    tmp[j] = (mn < DOUT) ? wo[(32 + q8 + j)*DOUT + mn] : 0.0f;
  make_frag1(tmp, Woh1);

  const float e0a = b10[n] * C2L2E, e0b = b20[n] * C2L2E;
  const float e1a = b11[n] * C2L2E, e1b = b21[n] * C2L2E;
  const float e2a = b12[n] * C2L2E, e2b = b22[n];
  const v4f E0A = {e0a, e0a, e0a, e0a}, E0B = {e0b, e0b, e0b, e0b};
  const v4f E1A = {e1a, e1a, e1a, e1a}, E1B = {e1b, e1b, e1b, e1b};
  const v4f E2A = {e2a, e2a, e2a, e2a}, E2B = {e2b, e2b, e2b, e2b};
  const float bsa = ba[u] * L2E;     // alpha = exp2(pA)
  const float bsb = bb[u] * C2L2E;   // beta  = tanh_from_arg(pB)
  const v4f BSA4 = {bsa, bsa, bsa, bsa};
  const v4f BSB4 = {bsb, bsb, bsb, bsb};
  const v4f Z4   = {0.f, 0.f, 0.f, 0.f};

  float* alpE  = alph + ((size_t)(sgbase + qd*4) * TB) * UNITS + u;
  float* alpO  = alph + ((size_t)(sgbase + SPT + qd*4) * TB) * UNITS + u;
  float* outpE = outs + ((size_t)(sgbase + qd*4) * TB) * DOUT + mn;
  float* outpO = outs + ((size_t)(sgbase + SPT + qd*4) * TB) * DOUT + mn;

  // ---------------- init ----------------
  for (int i = tid; i < 2*2*SPT*LDK0; i += 512) (&c0s[0][0][0])[i] = (_Float16)0.0f;
  __syncthreads();

  float hregE[4], hregO[4];
  if (wv < 4){
    #pragma unroll
    for (int r = 0; r < 4; r++){
      int s = qd*4 + r;
      float vE = initF[(size_t)(sgbase + s)*(2 + UNITS) + 2 + u];
      float vO = initF[(size_t)(sgbase + SPT + s)*(2 + UNITS) + 2 + u];
      hregE[r] = vE;
      hregO[r] = vO;
      c0s[0][0][s*LDK0 + 8 + u] = (_Float16)vE;
      c0s[1][0][s*LDK0 + 8 + u] = (_Float16)vO;
    }
  }
  // wave 4: lanes 0-15 own tile E samples, lanes 16-31 tile O samples
  float xv0=0, xv1=0, xv2=0, xv3=0, xv4=0, xv5=0;
  if (wv == 4 && ln < 32){
    const int tl = ln >> 4, s = ln & 15;
    const v2f* xp2 = (const v2f*)(x + (size_t)(sgbase + tl*SPT + s)*TB*D_IN);
    v2f A = xp2[0], Bv = xp2[1], C = xp2[2];
    float nv = sqrtf(A[0]*A[0] + A[1]*A[1] + Bv[0]*Bv[0] + Bv[1]*Bv[1] + C[0]*C[0] + C[1]*C[1]);
    nrms[tl][0][s] = nv * NEGL2E;
    float inv = 1.0f / (nv + EPSF);
    _Float16* cw = &c0s[tl][0][0];
    cw[s*LDK0 + 0] = (_Float16)(A[0]*inv);
    cw[s*LDK0 + 1] = (_Float16)(A[1]*inv);
    cw[s*LDK0 + 2] = (_Float16)(Bv[0]*inv);
    cw[s*LDK0 + 3] = (_Float16)(Bv[1]*inv);
    cw[s*LDK0 + 4] = (_Float16)(C[0]*inv);
    cw[s*LDK0 + 5] = (_Float16)(C[1]*inv);
    v2f D = xp2[3], E = xp2[4], F = xp2[5];                       // x(t=1)
    xv0 = D[0]; xv1 = D[1]; xv2 = E[0]; xv3 = E[1]; xv4 = F[0]; xv5 = F[1];
  }
  __syncthreads();

  // ---------------- O warm-up: A(0), B(0) ----------------
  PH_A(c0s[1][0], cPs[1]);
  BARRIER_LDS();
  PH_B(cPs[1], cQs[1]);
  BARRIER_LDS();

  // ============ main loop: each iteration advances BOTH tiles one step =========
  // int1: E.A(t)   + O.C(t)
  // int2: E.B(t)   + O.D(t)  (+ O.xnorm(t+1), O.wout(t-1))
  // int3: E.C(t)   + O.A(t+1)
  // int4: E.D(t)   + O.B(t+1) (+ E.xnorm(t+1), E.wout(t-1))
  for (int t = 0; t < TB; t++){
    const int p = t & 1;
    const _Float16* c0rE = c0s[0][p];
    _Float16* c0wE = c0s[0][p ^ 1];
    const _Float16* c0rO = c0s[1][p];
    _Float16* c0wO = c0s[1][p ^ 1];

    // ---- int1 ----
    PH_A(c0rE, cPs[0]);
    PH_C(cQs[1], cGs[1]);
    BARRIER_LDS();

    // ---- int2 ----
    PH_B(cPs[0], cQs[0]);
    if (wv < 4){
      PH_D(cGs[1], c0wO, nrms[1][p], hregO, alpO);
    } else if (wv == 7){
      if (t > 0) WOUT(c0rO, t - 1, outpO);
    } else if (wv == 4 && (ln >> 4) == 1){
      XNORM(c0wO, nrms[1][p ^ 1], SPT);
    }
    BARRIER_LDS();

    // ---- int3 ----
    PH_C(cQs[0], cGs[0]);
    if (t < TB - 1){
      PH_A(c0wO, cPs[1]);          // O.A(t+1): c0s[1][(t+1)&1] == c0wO
    }
    BARRIER_LDS();

    // ---- int4 ----
    if (t < TB - 1){
      PH_B(cPs[1], cQs[1]);        // O.B(t+1)
    }
    if (wv < 4){
      PH_D(cGs[0], c0wE, nrms[0][p], hregE, alpE);
    } else if (wv == 7){
      if (t > 0) WOUT(c0rE, t - 1, outpE);
    } else if (wv == 4 && (ln >> 4) == 0){
      XNORM(c0wE, nrms[0][p ^ 1], 0);
    }
    BARRIER_LDS();
  }

  // final wout(TB-1) for both tiles: h(TB-1) sits in c0s[*][0] (TB even)
  if (wv == 7){
    WOUT(c0s[0][0], TB - 1, outpE);
    WOUT(c0s[1][0], TB - 1, outpO);
  }
}

extern "C" void kernel_launch(void* const* d_in, const int* in_sizes, int n_in,
                              void* d_out, int out_size, void* d_ws, size_t ws_size,
                              hipStream_t stream) {
  const float* x    = (const float*)d_in[0];
  const float* iF   = (const float*)d_in[1];
  const float* w10  = (const float*)d_in[2];
  const float* b10  = (const float*)d_in[3];
  const float* w20  = (const float*)d_in[4];
  const float* b20  = (const float*)d_in[5];
  const float* w11  = (const float*)d_in[6];
  const float* b11  = (const float*)d_in[7];
  const float* w21  = (const float*)d_in[8];
  const float* b21  = (const float*)d_in[9];
  const float* w12  = (const float*)d_in[10];
  const float* b12  = (const float*)d_in[11];
  const float* w22  = (const float*)d_in[12];
  const float* b22  = (const float*)d_in[13];
  const float* wa   = (const float*)d_in[14];
  const float* ba   = (const float*)d_in[15];
  const float* wb   = (const float*)d_in[16];
  const float* bb   = (const float*)d_in[17];
  const float* wo   = (const float*)d_in[18];

  float* outs = (float*)d_out;
  float* alph = outs + (size_t)NB*TB*DOUT;

  lmsc_kernel<<<NB/SPB, 512, 0, stream>>>(x, iF,
      w10, b10, w20, b20, w11, b11, w21, b21, w12, b12, w22, b22,
      wa, ba, wb, bb, wo, outs, alph);
}